// Round 4
// baseline (105.138 us; speedup 1.0000x reference)
//
#include <hip/hip_runtime.h>

// EulerRNNCell — Genois qubit SDE Euler-Maruyama rollout.
// B=512 batch, NUM_TRAJ=64 trajectories/batch, T-1=255 steps.
// One block (1 wave, 64 threads) per batch element; thread j runs
// trajectory n = j*512 + b; mean over 64 trajectories = wave shuffle reduce.
//
// R4: float4 loads (2 steps per load) — halves memory txn count (64 distinct
// lines per wave-load is the binding cost at 2 waves/CU). Row byte offset is
// n*2040, and n&1 == b&1 (512 even), so 16B alignment is BLOCK-uniform:
// even b -> 127 float4 pairs + float2 tail; odd b -> float2 head + 127 pairs.
//
// Output layout (floats): [0,3584) = out[512,7] (probs ++ inputs);
// rho real plane at [3584,5632); imag plane at [5632,7680) if room.

#define BATCH   512
#define NTRAJ   64
#define TSTEPS  255

__device__ __forceinline__ void sde_step(float& x1, float& x2, float& x3,
                                         float w1, float w2, float omega)
{
    const float HG = 0.55f;                    // 0.5 * GAMMA
    const float K  = 0.44497190922573976f;     // sqrt(GAMMA*ETA/2)
    const float SD = 0.0625f;                  // sqrt(DT) = 2^-4 (exact)
    const float DT = 0.00390625f;              // 2^-8

    const float d1 = w1 * SD;
    const float d2 = w2 * SD;

    const float ax = -HG * x1;
    const float ay = -omega * x3 - HG * x2;
    const float az = omega * x2;

    const float bx = K * (-x1 * x3 * d1 + x2 * d2);
    const float by = K * (-x2 * x3 * d1 - x1 * d2);
    const float bz = K * ((1.0f - x3 * x3) * d1);

    const float y1 = x1 + DT * ax + bx;
    const float y2 = x2 + DT * ay + by;
    const float y3 = x3 + DT * az + bz;
    x1 = y1; x2 = y2; x3 = y3;
}

__global__ __launch_bounds__(64) void euler_rollout_kernel(
    const float* __restrict__ inputs,   // [512,1]
    const float* __restrict__ bloch0,   // [3]
    const float* __restrict__ wvec,     // [32768, 255, 2]
    float* __restrict__ out,            // [out_size]
    int out_size)
{
    const int b = blockIdx.x;           // batch index
    const int j = threadIdx.x;          // trajectory replica 0..63
    const long long n = (long long)j * BATCH + b;

    const float omega = inputs[b] + 1e-8f;

    float x1 = bloch0[0];
    float x2 = bloch0[1];
    float x3 = bloch0[2];

    // row of 255 float2 noise pairs for this trajectory (8B aligned;
    // 16B aligned iff n even iff b even — block-uniform)
    const float2* __restrict__ wrow =
        reinterpret_cast<const float2*>(wvec) + n * TSTEPS;

    if ((b & 1) == 0) {
        // 16B-aligned from the start: 127 float4 (2 steps each) + float2 tail
        const float4* __restrict__ w4 = reinterpret_cast<const float4*>(wrow);
#pragma unroll
        for (int p = 0; p < 127; ++p) {
            const float4 w = w4[p];
            sde_step(x1, x2, x3, w.x, w.y, omega);
            sde_step(x1, x2, x3, w.z, w.w, omega);
        }
        const float2 wt = wrow[254];
        sde_step(x1, x2, x3, wt.x, wt.y, omega);
    } else {
        // peel one float2 step, then 16B-aligned: 127 float4 pairs
        const float2 wh = wrow[0];
        sde_step(x1, x2, x3, wh.x, wh.y, omega);
        const float4* __restrict__ w4 = reinterpret_cast<const float4*>(wrow + 1);
#pragma unroll
        for (int p = 0; p < 127; ++p) {
            const float4 w = w4[p];
            sde_step(x1, x2, x3, w.x, w.y, omega);
            sde_step(x1, x2, x3, w.z, w.w, omega);
        }
    }

    // wave-wide sum over the 64 trajectories of this batch element
#pragma unroll
    for (int off = 32; off > 0; off >>= 1) {
        x1 += __shfl_xor(x1, off);
        x2 += __shfl_xor(x2, off);
        x3 += __shfl_xor(x3, off);
    }

    if (j == 0) {
        const float inv = 1.0f / (float)NTRAJ;
        const float xm1 = x1 * inv;
        const float xm2 = x2 * inv;
        const float xm3 = x3 * inv;

        float px = 0.5f * (xm1 + 1.0f);
        float py = 0.5f * (xm2 + 1.0f);
        float pz = 0.5f * (xm3 + 1.0f);

        float p0 = fminf(fmaxf(px, 0.0f), 1.0f);
        float p1 = fminf(fmaxf(1.0f - px, 0.0f), 1.0f);
        float p2 = fminf(fmaxf(py, 0.0f), 1.0f);
        float p3 = fminf(fmaxf(1.0f - py, 0.0f), 1.0f);
        float p4 = fminf(fmaxf(pz, 0.0f), 1.0f);
        float p5 = fminf(fmaxf(1.0f - pz, 0.0f), 1.0f);

        float* o = out + (long long)b * 7;
        o[0] = p0; o[1] = p1; o[2] = p2; o[3] = p3; o[4] = p4; o[5] = p5;
        o[6] = inputs[b];

        // rho real parts: [(1+z)/2, x/2, x/2, (1-z)/2] at [3584, 5632)
        float* rre = out + BATCH * 7 + (long long)b * 4;
        rre[0] = (1.0f + xm3) * 0.5f;
        rre[1] = xm1 * 0.5f;
        rre[2] = xm1 * 0.5f;
        rre[3] = (1.0f - xm3) * 0.5f;

        // rho imag parts: [0, -y/2, y/2, 0] at [5632, 7680) if buffer has room
        if (out_size >= BATCH * 7 + BATCH * 8) {
            float* rim = out + BATCH * 7 + BATCH * 4 + (long long)b * 4;
            rim[0] = 0.0f;
            rim[1] = -xm2 * 0.5f;
            rim[2] = xm2 * 0.5f;
            rim[3] = 0.0f;
        }
    }
}

extern "C" void kernel_launch(void* const* d_in, const int* in_sizes, int n_in,
                              void* d_out, int out_size, void* d_ws, size_t ws_size,
                              hipStream_t stream) {
    const float* inputs = (const float*)d_in[0];   // [512,1]
    const float* bloch0 = (const float*)d_in[1];   // [3]
    const float* wvec   = (const float*)d_in[2];   // [32768,255,2]
    float* out = (float*)d_out;

    euler_rollout_kernel<<<dim3(BATCH), dim3(64), 0, stream>>>(
        inputs, bloch0, wvec, out, out_size);
}